// Round 1
// baseline (101.299 us; speedup 1.0000x reference)
//
#include <hip/hip_runtime.h>
#include <hip/hip_bf16.h>

// Self-attention, fused QKV: x[4,2048,1024] f32, Wq/Wk/Wv[1024,64] f32 -> out[4,2048,64] f32
// Strategy: bf16 MFMA (16x16x32) everywhere, fp32 accumulation.
//   K1: W -> Wt bf16 [192][1024] (k-major, so MFMA B-frags are contiguous 16B loads)
//   K2: QKV projection -> Q,K bf16 [8192][64]; V stored transposed Vt [4][64][2048]
//   K3: flash attention, 1 wave / 16 queries, KV tiles of 64, online softmax

typedef __attribute__((ext_vector_type(8))) short bf16x8;
typedef __attribute__((ext_vector_type(4))) float f32x4;

__device__ __forceinline__ short f2bf(float f) {
    union { float f; unsigned u; } v; v.f = f;
    unsigned r = v.u + 0x7FFF + ((v.u >> 16) & 1);   // round-to-nearest-even
    return (short)(r >> 16);
}

// ---------------- K1: weight transpose + bf16 convert ----------------
// Wt[n][d], n in [0,192): n<64 -> Wq col n; <128 -> Wk; else Wv.
__global__ __launch_bounds__(256) void wtrans(const float* __restrict__ Wq,
                                              const float* __restrict__ Wk,
                                              const float* __restrict__ Wv,
                                              short* __restrict__ Wt) {
    int idx = blockIdx.x * 256 + threadIdx.x;      // 0 .. 192*1024-1
    int n = idx >> 10;
    int d = idx & 1023;
    const float* W = (n < 64) ? Wq : (n < 128) ? Wk : Wv;
    Wt[idx] = f2bf(W[d * 64 + (n & 63)]);
}

// ---------------- K2: QKV projection ----------------
// block = 256 thr (4 waves). Block tile: 32 rows x 192 cols.
// wave w: rows (w&1)*16, cols (w>>1)*96 (6 n-tiles of 16).
__global__ __launch_bounds__(256) void qkv_proj(const float* __restrict__ x,
                                                const short* __restrict__ Wt,
                                                short* __restrict__ Q,
                                                short* __restrict__ K,
                                                short* __restrict__ Vt) {
    int wid  = threadIdx.x >> 6;
    int lane = threadIdx.x & 63;
    int l15 = lane & 15, lg = lane >> 4;
    int mbase = blockIdx.x * 32 + (wid & 1) * 16;
    int nbase = (wid >> 1) * 96;
    int row = mbase + l15;

    f32x4 acc[6];
    #pragma unroll
    for (int t = 0; t < 6; ++t) acc[t] = (f32x4){0.f, 0.f, 0.f, 0.f};

    for (int d0 = 0; d0 < 1024; d0 += 32) {
        const float* xp = x + row * 1024 + d0 + lg * 8;
        float4 x0 = *(const float4*)xp;
        float4 x1 = *(const float4*)(xp + 4);
        bf16x8 a;
        a[0] = f2bf(x0.x); a[1] = f2bf(x0.y); a[2] = f2bf(x0.z); a[3] = f2bf(x0.w);
        a[4] = f2bf(x1.x); a[5] = f2bf(x1.y); a[6] = f2bf(x1.z); a[7] = f2bf(x1.w);
        #pragma unroll
        for (int t = 0; t < 6; ++t) {
            int n = nbase + t * 16 + l15;
            bf16x8 b = *(const bf16x8*)(Wt + n * 1024 + d0 + lg * 8);
            acc[t] = __builtin_amdgcn_mfma_f32_16x16x32_bf16(a, b, acc[t], 0, 0, 0);
        }
    }

    #pragma unroll
    for (int t = 0; t < 6; ++t) {
        int n = nbase + t * 16 + l15;
        #pragma unroll
        for (int r = 0; r < 4; ++r) {
            int m = mbase + lg * 4 + r;
            short v = f2bf(acc[t][r]);
            if (n < 64) {
                Q[m * 64 + n] = v;
            } else if (n < 128) {
                K[m * 64 + (n - 64)] = v;
            } else {
                int b_ = m >> 11, s_ = m & 2047;
                Vt[(b_ * 64 + (n - 128)) * 2048 + s_] = v;
            }
        }
    }
}

// ---------------- K3: flash attention ----------------
// grid = 4 * 128 blocks, 64 threads (1 wave). Each wave: 16 queries, full 2048 keys.
__global__ __launch_bounds__(64) void attn(const short* __restrict__ Q,
                                           const short* __restrict__ K,
                                           const short* __restrict__ Vt,
                                           float* __restrict__ out) {
    __shared__ short P_lds[16 * 64];   // [q][p]
    int lane = threadIdx.x;
    int l15 = lane & 15, lg = lane >> 4;
    int b_ = blockIdx.x >> 7;
    int q0 = (blockIdx.x & 127) * 16;
    const short* Kb = K + b_ * 2048 * 64;
    const short* Vb = Vt + b_ * 64 * 2048;

    const short* Qp = Q + (b_ * 2048 + q0 + l15) * 64 + lg * 8;
    bf16x8 aq0 = *(const bf16x8*)Qp;
    bf16x8 aq1 = *(const bf16x8*)(Qp + 32);

    f32x4 acc[4];
    #pragma unroll
    for (int t = 0; t < 4; ++t) acc[t] = (f32x4){0.f, 0.f, 0.f, 0.f};
    float m_run[4], l_run[4];
    #pragma unroll
    for (int r = 0; r < 4; ++r) { m_run[r] = -INFINITY; l_run[r] = 0.f; }
    const float LOG2E = 1.44269504f;

    for (int kv = 0; kv < 2048; kv += 64) {
        // S = Q K^T (scaled). s[kt][r]: query = q0+lg*4+r, key = kv+kt*16+l15
        f32x4 s[4];
        #pragma unroll
        for (int kt = 0; kt < 4; ++kt) {
            const short* Kp = Kb + (kv + kt * 16 + l15) * 64 + lg * 8;
            bf16x8 bk0 = *(const bf16x8*)Kp;
            bf16x8 bk1 = *(const bf16x8*)(Kp + 32);
            f32x4 z = (f32x4){0.f, 0.f, 0.f, 0.f};
            z = __builtin_amdgcn_mfma_f32_16x16x32_bf16(aq0, bk0, z, 0, 0, 0);
            s[kt] = __builtin_amdgcn_mfma_f32_16x16x32_bf16(aq1, bk1, z, 0, 0, 0);
        }
        #pragma unroll
        for (int kt = 0; kt < 4; ++kt)
            #pragma unroll
            for (int r = 0; r < 4; ++r) s[kt][r] *= 0.125f;

        // online softmax (wave-parallel: reduce across the 16 key-lanes)
        float corr[4];
        #pragma unroll
        for (int r = 0; r < 4; ++r) {
            float mt = fmaxf(fmaxf(s[0][r], s[1][r]), fmaxf(s[2][r], s[3][r]));
            mt = fmaxf(mt, __shfl_xor(mt, 1));
            mt = fmaxf(mt, __shfl_xor(mt, 2));
            mt = fmaxf(mt, __shfl_xor(mt, 4));
            mt = fmaxf(mt, __shfl_xor(mt, 8));
            float mn = fmaxf(m_run[r], mt);
            float c = exp2f((m_run[r] - mn) * LOG2E);
            m_run[r] = mn;
            corr[r] = c;
            float rs = 0.f;
            #pragma unroll
            for (int kt = 0; kt < 4; ++kt) {
                float p = exp2f((s[kt][r] - mn) * LOG2E);
                s[kt][r] = p;
                rs += p;
            }
            rs += __shfl_xor(rs, 1);
            rs += __shfl_xor(rs, 2);
            rs += __shfl_xor(rs, 4);
            rs += __shfl_xor(rs, 8);
            l_run[r] = l_run[r] * c + rs;
            #pragma unroll
            for (int t = 0; t < 4; ++t) acc[t][r] *= c;
        }

        // P -> LDS (re-layout C-frag -> A-operand)
        __syncthreads();
        #pragma unroll
        for (int kt = 0; kt < 4; ++kt) {
            int p = kt * 16 + l15;
            #pragma unroll
            for (int r = 0; r < 4; ++r)
                P_lds[(lg * 4 + r) * 64 + p] = f2bf(s[kt][r]);
        }
        __syncthreads();

        // PV: acc[t] += P[16q x 32p] * V[32p x 16dk]
        #pragma unroll
        for (int ps = 0; ps < 2; ++ps) {
            bf16x8 ap = *(const bf16x8*)&P_lds[l15 * 64 + ps * 32 + lg * 8];
            #pragma unroll
            for (int t = 0; t < 4; ++t) {
                const short* Vp = Vb + (t * 16 + l15) * 2048 + kv + ps * 32 + lg * 8;
                bf16x8 bv = *(const bf16x8*)Vp;
                acc[t] = __builtin_amdgcn_mfma_f32_16x16x32_bf16(ap, bv, acc[t], 0, 0, 0);
            }
        }
    }

    #pragma unroll
    for (int t = 0; t < 4; ++t) {
        int n = t * 16 + l15;
        #pragma unroll
        for (int r = 0; r < 4; ++r) {
            int m = q0 + lg * 4 + r;
            out[(b_ * 2048 + m) * 64 + n] = acc[t][r] / l_run[r];
        }
    }
}

extern "C" void kernel_launch(void* const* d_in, const int* in_sizes, int n_in,
                              void* d_out, int out_size, void* d_ws, size_t ws_size,
                              hipStream_t stream) {
    const float* x  = (const float*)d_in[0];
    const float* Wq = (const float*)d_in[1];
    const float* Wk = (const float*)d_in[2];
    const float* Wv = (const float*)d_in[3];
    float* out = (float*)d_out;

    char* ws = (char*)d_ws;
    short* Wt = (short*)ws;                              // 192*1024*2   = 393216 B
    short* Q  = (short*)(ws + 393216);                   // 8192*64*2    = 1048576 B
    short* K  = (short*)(ws + 393216 + 1048576);         // 1048576 B
    short* Vt = (short*)(ws + 393216 + 2 * 1048576);     // 1048576 B   (total ~3.4 MB)

    hipLaunchKernelGGL(wtrans,   dim3(768), dim3(256), 0, stream, Wq, Wk, Wv, Wt);
    hipLaunchKernelGGL(qkv_proj, dim3(256), dim3(256), 0, stream, x, Wt, Q, K, Vt);
    hipLaunchKernelGGL(attn,     dim3(512), dim3(64),  0, stream, Q, K, Vt, out);
}

// Round 2
// 76.832 us; speedup vs baseline: 1.3184x; 1.3184x over previous
//
#include <hip/hip_runtime.h>
#include <hip/hip_bf16.h>

// Self-attention, fused QKV: x[4,2048,1024] f32, Wq/Wk/Wv[1024,64] f32 -> out[4,2048,64] f32
// bf16 MFMA (16x16x32), fp32 accumulation.
//   K1: W -> Wt bf16 [192][1024] (k-major)
//   K2: QKV projection, k-split x2, x read ONCE -> Q,K bf16 [8192][64]; V transposed Vt[4][64][2048]
//   K3: flash attention, block = 8 waves x 16 queries, split-KV x8 (256 keys/wave),
//       deterministic LDS combine.

typedef __attribute__((ext_vector_type(8))) short bf16x8;
typedef __attribute__((ext_vector_type(4))) float f32x4;

#define LOG2E 1.44269504f

__device__ __forceinline__ short f2bf(float f) {
    union { float f; unsigned u; } v; v.f = f;
    unsigned r = v.u + 0x7FFF + ((v.u >> 16) & 1);   // round-to-nearest-even
    return (short)(r >> 16);
}

// ---------------- K1: weight transpose + bf16 convert ----------------
__global__ __launch_bounds__(256) void wtrans(const float* __restrict__ Wq,
                                              const float* __restrict__ Wk,
                                              const float* __restrict__ Wv,
                                              short* __restrict__ Wt) {
    int idx = blockIdx.x * 256 + threadIdx.x;      // 0 .. 192*1024-1
    int n = idx >> 10;
    int d = idx & 1023;
    const float* W = (n < 64) ? Wq : (n < 128) ? Wk : Wv;
    Wt[idx] = f2bf(W[d * 64 + (n & 63)]);
}

// ---------------- K2: QKV projection ----------------
// grid 256 blocks x 256 thr. Block tile: 32 rows x 192 cols, K=1024.
// wave wid: rowg = wid&1 (16 rows), khalf = wid>>1 (512 of K). x read exactly once.
__global__ __launch_bounds__(256) void qkv_proj(const float* __restrict__ x,
                                                const short* __restrict__ Wt,
                                                short* __restrict__ Q,
                                                short* __restrict__ K,
                                                short* __restrict__ Vt) {
    __shared__ float accs[2][16][200];
    int wid  = threadIdx.x >> 6;
    int lane = threadIdx.x & 63;
    int l15 = lane & 15, lg = lane >> 4;
    int rowg = wid & 1, kh = wid >> 1;
    int mbase = blockIdx.x * 32 + rowg * 16;
    int row = mbase + l15;

    f32x4 acc[12];
    #pragma unroll
    for (int t = 0; t < 12; ++t) acc[t] = (f32x4){0.f, 0.f, 0.f, 0.f};

    for (int d0 = kh * 512; d0 < kh * 512 + 512; d0 += 32) {
        const float* xp = x + row * 1024 + d0 + lg * 8;
        float4 x0 = *(const float4*)xp;
        float4 x1 = *(const float4*)(xp + 4);
        bf16x8 a;
        a[0] = f2bf(x0.x); a[1] = f2bf(x0.y); a[2] = f2bf(x0.z); a[3] = f2bf(x0.w);
        a[4] = f2bf(x1.x); a[5] = f2bf(x1.y); a[6] = f2bf(x1.z); a[7] = f2bf(x1.w);
        #pragma unroll
        for (int t = 0; t < 12; ++t) {
            bf16x8 b = *(const bf16x8*)(Wt + (t * 16 + l15) * 1024 + d0 + lg * 8);
            acc[t] = __builtin_amdgcn_mfma_f32_16x16x32_bf16(a, b, acc[t], 0, 0, 0);
        }
    }

    if (kh == 1) {
        #pragma unroll
        for (int t = 0; t < 12; ++t)
            #pragma unroll
            for (int r = 0; r < 4; ++r)
                accs[rowg][lg * 4 + r][t * 16 + l15] = acc[t][r];
    }
    __syncthreads();
    if (kh == 0) {
        #pragma unroll
        for (int t = 0; t < 12; ++t) {
            int n = t * 16 + l15;
            #pragma unroll
            for (int r = 0; r < 4; ++r) {
                int m = mbase + lg * 4 + r;
                float v = acc[t][r] + accs[rowg][lg * 4 + r][n];
                short s = f2bf(v);
                if (n < 64) {
                    Q[m * 64 + n] = s;
                } else if (n < 128) {
                    K[m * 64 + (n - 64)] = s;
                } else {
                    int b_ = m >> 11, s_ = m & 2047;
                    Vt[(b_ * 64 + (n - 128)) * 2048 + s_] = s;
                }
            }
        }
    }
}

// ---------------- K3: flash attention, split-KV ----------------
// grid = 4*128 = 512 blocks, 512 thr (8 waves). Each wave: same 16 queries, 256-key slice.
__global__ __launch_bounds__(512, 4) void attn(const short* __restrict__ Q,
                                               const short* __restrict__ K,
                                               const short* __restrict__ Vt,
                                               float* __restrict__ out) {
    __shared__ float accw[8][16][65];    // scaled partial outputs
    __shared__ short P_lds[8][16][72];   // per-wave P relayout (stride 72 -> 144B, 16B aligned)
    __shared__ float Mw[8][16];
    __shared__ float Lw[8][16];
    __shared__ float Ltot[16];

    int tid = threadIdx.x, wid = tid >> 6, lane = tid & 63;
    int l15 = lane & 15, lg = lane >> 4;
    int b_ = blockIdx.x >> 7;
    int q0 = (blockIdx.x & 127) * 16;
    const short* Kb = K + b_ * 2048 * 64;
    const short* Vb = Vt + b_ * 64 * 2048;

    const short* Qp = Q + (b_ * 2048 + q0 + l15) * 64 + lg * 8;
    bf16x8 aq0 = *(const bf16x8*)Qp;
    bf16x8 aq1 = *(const bf16x8*)(Qp + 32);

    f32x4 acc[4];
    #pragma unroll
    for (int t = 0; t < 4; ++t) acc[t] = (f32x4){0.f, 0.f, 0.f, 0.f};
    float m_run[4], l_run[4];
    #pragma unroll
    for (int r = 0; r < 4; ++r) { m_run[r] = -INFINITY; l_run[r] = 0.f; }

    int kv0 = wid * 256;
    for (int kv = kv0; kv < kv0 + 256; kv += 64) {
        // S = Q K^T (scaled). s[kt][r]: query = q0+lg*4+r, key = kv+kt*16+l15
        f32x4 s[4];
        #pragma unroll
        for (int kt = 0; kt < 4; ++kt) {
            const short* Kp = Kb + (kv + kt * 16 + l15) * 64 + lg * 8;
            bf16x8 bk0 = *(const bf16x8*)Kp;
            bf16x8 bk1 = *(const bf16x8*)(Kp + 32);
            f32x4 z = (f32x4){0.f, 0.f, 0.f, 0.f};
            z = __builtin_amdgcn_mfma_f32_16x16x32_bf16(aq0, bk0, z, 0, 0, 0);
            s[kt] = __builtin_amdgcn_mfma_f32_16x16x32_bf16(aq1, bk1, z, 0, 0, 0);
        }
        #pragma unroll
        for (int kt = 0; kt < 4; ++kt)
            #pragma unroll
            for (int r = 0; r < 4; ++r) s[kt][r] *= 0.125f;

        // online softmax (reduce across the 16 key-lanes)
        #pragma unroll
        for (int r = 0; r < 4; ++r) {
            float mt = fmaxf(fmaxf(s[0][r], s[1][r]), fmaxf(s[2][r], s[3][r]));
            mt = fmaxf(mt, __shfl_xor(mt, 1));
            mt = fmaxf(mt, __shfl_xor(mt, 2));
            mt = fmaxf(mt, __shfl_xor(mt, 4));
            mt = fmaxf(mt, __shfl_xor(mt, 8));
            float mn = fmaxf(m_run[r], mt);
            float c = exp2f((m_run[r] - mn) * LOG2E);
            m_run[r] = mn;
            float rs = 0.f;
            #pragma unroll
            for (int kt = 0; kt < 4; ++kt) {
                float p = exp2f((s[kt][r] - mn) * LOG2E);
                s[kt][r] = p;
                rs += p;
            }
            rs += __shfl_xor(rs, 1);
            rs += __shfl_xor(rs, 2);
            rs += __shfl_xor(rs, 4);
            rs += __shfl_xor(rs, 8);
            l_run[r] = l_run[r] * c + rs;
            #pragma unroll
            for (int t = 0; t < 4; ++t) acc[t][r] *= c;
        }

        // P -> LDS (per-wave region; barriers keep write->read ordered)
        __syncthreads();
        #pragma unroll
        for (int kt = 0; kt < 4; ++kt) {
            int p = kt * 16 + l15;
            #pragma unroll
            for (int r = 0; r < 4; ++r)
                P_lds[wid][lg * 4 + r][p] = f2bf(s[kt][r]);
        }
        __syncthreads();

        // PV: acc[t] += P[16q x 32p] * V[32p x 16dk]
        #pragma unroll
        for (int ps = 0; ps < 2; ++ps) {
            bf16x8 ap = *(const bf16x8*)&P_lds[wid][l15][ps * 32 + lg * 8];
            #pragma unroll
            for (int t = 0; t < 4; ++t) {
                const short* Vp = Vb + (t * 16 + l15) * 2048 + kv + ps * 32 + lg * 8;
                bf16x8 bv = *(const bf16x8*)Vp;
                acc[t] = __builtin_amdgcn_mfma_f32_16x16x32_bf16(ap, bv, acc[t], 0, 0, 0);
            }
        }
    }

    // ---- deterministic split-KV combine ----
    if (l15 == 0) {
        #pragma unroll
        for (int r = 0; r < 4; ++r) {
            Mw[wid][lg * 4 + r] = m_run[r];
            Lw[wid][lg * 4 + r] = l_run[r];
        }
    }
    __syncthreads();

    float fac[4], mtot[4];
    #pragma unroll
    for (int r = 0; r < 4; ++r) {
        int row = lg * 4 + r;
        float m = Mw[0][row];
        #pragma unroll
        for (int w = 1; w < 8; ++w) m = fmaxf(m, Mw[w][row]);
        mtot[r] = m;
        fac[r] = exp2f((m_run[r] - m) * LOG2E);
    }
    #pragma unroll
    for (int t = 0; t < 4; ++t)
        #pragma unroll
        for (int r = 0; r < 4; ++r)
            accw[wid][lg * 4 + r][t * 16 + l15] = acc[t][r] * fac[r];

    if (wid == 0 && l15 == 0) {
        #pragma unroll
        for (int r = 0; r < 4; ++r) {
            int row = lg * 4 + r;
            float L = 0.f;
            #pragma unroll
            for (int w = 0; w < 8; ++w)
                L += Lw[w][row] * exp2f((Mw[w][row] - mtot[r]) * LOG2E);
            Ltot[row] = L;
        }
    }
    __syncthreads();

    #pragma unroll
    for (int j = 0; j < 2; ++j) {
        int o = tid + j * 512;
        int row = o >> 6, col = o & 63;
        float ssum = 0.f;
        #pragma unroll
        for (int w = 0; w < 8; ++w) ssum += accw[w][row][col];
        out[(b_ * 2048 + q0 + row) * 64 + col] = ssum / Ltot[row];
    }
}

extern "C" void kernel_launch(void* const* d_in, const int* in_sizes, int n_in,
                              void* d_out, int out_size, void* d_ws, size_t ws_size,
                              hipStream_t stream) {
    const float* x  = (const float*)d_in[0];
    const float* Wq = (const float*)d_in[1];
    const float* Wk = (const float*)d_in[2];
    const float* Wv = (const float*)d_in[3];
    float* out = (float*)d_out;

    char* ws = (char*)d_ws;
    short* Wt = (short*)ws;                              // 192*1024*2   = 393216 B
    short* Q  = (short*)(ws + 393216);                   // 8192*64*2    = 1048576 B
    short* K  = (short*)(ws + 393216 + 1048576);         // 1048576 B
    short* Vt = (short*)(ws + 393216 + 2 * 1048576);     // 1048576 B   (total ~3.4 MB)

    hipLaunchKernelGGL(wtrans,   dim3(768), dim3(256), 0, stream, Wq, Wk, Wv, Wt);
    hipLaunchKernelGGL(qkv_proj, dim3(256), dim3(256), 0, stream, x, Wt, Q, K, Vt);
    hipLaunchKernelGGL(attn,     dim3(512), dim3(512), 0, stream, Q, K, Vt, out);
}

// Round 4
// 71.404 us; speedup vs baseline: 1.4187x; 1.0760x over previous
//
#include <hip/hip_runtime.h>
#include <hip/hip_bf16.h>

// Self-attention, fused QKV: x[4,2048,1024] f32, Wq/Wk/Wv[1024,64] f32 -> out[4,2048,64] f32
// bf16 MFMA (16x16x32), fp32 accumulation.
//   K1: W -> Wt bf16 [192][1024] (k-major)
//   K2: QKV projection, 512 blocks x 4 waves, k-split x4, x read ONCE.
//       Q written pre-scaled by 0.125*log2(e) so attn softmax is pure exp2.
//   K3: flash attention, block = 8 waves x 16 queries, split-KV x8 (256 keys/wave),
//       NO barriers in the KV loop (per-wave private LDS), deterministic combine.

typedef __attribute__((ext_vector_type(8))) short bf16x8;
typedef __attribute__((ext_vector_type(4))) float f32x4;

#define QSCALE 0.1803368801111832f   // 0.125 * log2(e); makes logits exp2-domain

__device__ __forceinline__ short f2bf(float f) {
    union { float f; unsigned u; } v; v.f = f;
    unsigned r = v.u + 0x7FFF + ((v.u >> 16) & 1);   // round-to-nearest-even
    return (short)(r >> 16);
}

// ---------------- K1: weight transpose + bf16 convert ----------------
__global__ __launch_bounds__(256) void wtrans(const float* __restrict__ Wq,
                                              const float* __restrict__ Wk,
                                              const float* __restrict__ Wv,
                                              short* __restrict__ Wt) {
    int idx = blockIdx.x * 256 + threadIdx.x;      // 0 .. 192*1024-1
    int n = idx >> 10;
    int d = idx & 1023;
    const float* W = (n < 64) ? Wq : (n < 128) ? Wk : Wv;
    Wt[idx] = f2bf(W[d * 64 + (n & 63)]);
}

// ---------------- K2: QKV projection ----------------
// grid 512 blocks x 256 thr (4 waves). Block: 16 rows x 192 cols, K=1024.
// wave wid = k-split index: K slice [wid*256, wid*256+256). x read exactly once.
__global__ __launch_bounds__(256) void qkv_proj(const float* __restrict__ x,
                                                const short* __restrict__ Wt,
                                                short* __restrict__ Q,
                                                short* __restrict__ K,
                                                short* __restrict__ Vt) {
    __shared__ float accs[3][16][196];
    int wid  = threadIdx.x >> 6;
    int lane = threadIdx.x & 63;
    int l15 = lane & 15, lg = lane >> 4;
    int mbase = blockIdx.x * 16;
    int row = mbase + l15;

    f32x4 acc[12];
    #pragma unroll
    for (int t = 0; t < 12; ++t) acc[t] = (f32x4){0.f, 0.f, 0.f, 0.f};

    int d0base = wid * 256;
    for (int d0 = d0base; d0 < d0base + 256; d0 += 32) {
        const float* xp = x + row * 1024 + d0 + lg * 8;
        float4 x0 = *(const float4*)xp;
        float4 x1 = *(const float4*)(xp + 4);
        bf16x8 a;
        a[0] = f2bf(x0.x); a[1] = f2bf(x0.y); a[2] = f2bf(x0.z); a[3] = f2bf(x0.w);
        a[4] = f2bf(x1.x); a[5] = f2bf(x1.y); a[6] = f2bf(x1.z); a[7] = f2bf(x1.w);
        #pragma unroll
        for (int t = 0; t < 12; ++t) {
            bf16x8 b = *(const bf16x8*)(Wt + (t * 16 + l15) * 1024 + d0 + lg * 8);
            acc[t] = __builtin_amdgcn_mfma_f32_16x16x32_bf16(a, b, acc[t], 0, 0, 0);
        }
    }

    if (wid != 0) {
        #pragma unroll
        for (int t = 0; t < 12; ++t)
            #pragma unroll
            for (int r = 0; r < 4; ++r)
                accs[wid - 1][lg * 4 + r][t * 16 + l15] = acc[t][r];
    }
    __syncthreads();
    if (wid == 0) {
        #pragma unroll
        for (int t = 0; t < 12; ++t) {
            int n = t * 16 + l15;
            #pragma unroll
            for (int r = 0; r < 4; ++r) {
                int qrow = lg * 4 + r;
                int m = mbase + qrow;
                float v = acc[t][r] + accs[0][qrow][n] + accs[1][qrow][n] + accs[2][qrow][n];
                if (n < 64) {
                    Q[m * 64 + n] = f2bf(v * QSCALE);
                } else if (n < 128) {
                    K[m * 64 + (n - 64)] = f2bf(v);
                } else {
                    int b_ = m >> 11, s_ = m & 2047;
                    Vt[(b_ * 64 + (n - 128)) * 2048 + s_] = f2bf(v);
                }
            }
        }
    }
}

// ---------------- K3: flash attention, split-KV ----------------
// grid = 4*128 = 512 blocks, 512 thr (8 waves). Each wave: same 16 queries, 256-key slice.
// Logits arrive pre-scaled to exp2 domain (Q carries 0.125*log2e).
__global__ __launch_bounds__(512) void attn(const short* __restrict__ Q,
                                            const short* __restrict__ K,
                                            const short* __restrict__ Vt,
                                            float* __restrict__ out) {
    __shared__ float accw[8][16][65];    // scaled partial outputs
    __shared__ short P_lds[8][16][72];   // per-wave P relayout (private per wave)
    __shared__ float Mw[8][16];
    __shared__ float Lw[8][16];
    __shared__ float Ltot[16];

    int tid = threadIdx.x, wid = tid >> 6, lane = tid & 63;
    int l15 = lane & 15, lg = lane >> 4;
    int b_ = blockIdx.x >> 7;
    int q0 = (blockIdx.x & 127) * 16;
    const short* Kb = K + b_ * 2048 * 64;
    const short* Vb = Vt + b_ * 64 * 2048;

    const short* Qp = Q + (b_ * 2048 + q0 + l15) * 64 + lg * 8;
    bf16x8 aq0 = *(const bf16x8*)Qp;
    bf16x8 aq1 = *(const bf16x8*)(Qp + 32);

    f32x4 acc[4];
    #pragma unroll
    for (int t = 0; t < 4; ++t) acc[t] = (f32x4){0.f, 0.f, 0.f, 0.f};
    float m_run[4], l_run[4];
    #pragma unroll
    for (int r = 0; r < 4; ++r) { m_run[r] = -INFINITY; l_run[r] = 0.f; }

    int kv0 = wid * 256;
    for (int kv = kv0; kv < kv0 + 256; kv += 64) {
        // S = Q K^T (exp2-domain logits). s[kt][r]: query = q0+lg*4+r, key = kv+kt*16+l15
        f32x4 s[4];
        #pragma unroll
        for (int kt = 0; kt < 4; ++kt) {
            const short* Kp = Kb + (kv + kt * 16 + l15) * 64 + lg * 8;
            bf16x8 bk0 = *(const bf16x8*)Kp;
            bf16x8 bk1 = *(const bf16x8*)(Kp + 32);
            f32x4 z = (f32x4){0.f, 0.f, 0.f, 0.f};
            z = __builtin_amdgcn_mfma_f32_16x16x32_bf16(aq0, bk0, z, 0, 0, 0);
            s[kt] = __builtin_amdgcn_mfma_f32_16x16x32_bf16(aq1, bk1, z, 0, 0, 0);
        }

        // online softmax in exp2 domain (reduce across the 16 key-lanes)
        #pragma unroll
        for (int r = 0; r < 4; ++r) {
            float mt = fmaxf(fmaxf(s[0][r], s[1][r]), fmaxf(s[2][r], s[3][r]));
            mt = fmaxf(mt, __shfl_xor(mt, 1));
            mt = fmaxf(mt, __shfl_xor(mt, 2));
            mt = fmaxf(mt, __shfl_xor(mt, 4));
            mt = fmaxf(mt, __shfl_xor(mt, 8));
            float mn = fmaxf(m_run[r], mt);
            float c = exp2f(m_run[r] - mn);
            m_run[r] = mn;
            float rs = 0.f;
            #pragma unroll
            for (int kt = 0; kt < 4; ++kt) {
                float p = exp2f(s[kt][r] - mn);
                s[kt][r] = p;
                rs += p;
            }
            rs += __shfl_xor(rs, 1);
            rs += __shfl_xor(rs, 2);
            rs += __shfl_xor(rs, 4);
            rs += __shfl_xor(rs, 8);
            l_run[r] = l_run[r] * c + rs;
            #pragma unroll
            for (int t = 0; t < 4; ++t) acc[t][r] *= c;
        }

        // P -> per-wave private LDS region (no cross-wave hazard: no barrier needed;
        // intra-wave write->read ordering is enforced by lgkmcnt)
        #pragma unroll
        for (int kt = 0; kt < 4; ++kt) {
            int p = kt * 16 + l15;
            #pragma unroll
            for (int r = 0; r < 4; ++r)
                P_lds[wid][lg * 4 + r][p] = f2bf(s[kt][r]);
        }

        // PV: acc[t] += P[16q x 32p] * V[32p x 16dk]
        #pragma unroll
        for (int ps = 0; ps < 2; ++ps) {
            bf16x8 ap = *(const bf16x8*)&P_lds[wid][l15][ps * 32 + lg * 8];
            #pragma unroll
            for (int t = 0; t < 4; ++t) {
                const short* Vp = Vb + (t * 16 + l15) * 2048 + kv + ps * 32 + lg * 8;
                bf16x8 bv = *(const bf16x8*)Vp;
                acc[t] = __builtin_amdgcn_mfma_f32_16x16x32_bf16(ap, bv, acc[t], 0, 0, 0);
            }
        }
    }

    // ---- deterministic split-KV combine ----
    if (l15 == 0) {
        #pragma unroll
        for (int r = 0; r < 4; ++r) {
            Mw[wid][lg * 4 + r] = m_run[r];
            Lw[wid][lg * 4 + r] = l_run[r];
        }
    }
    __syncthreads();

    float fac[4], mtot[4];
    #pragma unroll
    for (int r = 0; r < 4; ++r) {
        int row = lg * 4 + r;
        float m = Mw[0][row];
        #pragma unroll
        for (int w = 1; w < 8; ++w) m = fmaxf(m, Mw[w][row]);
        mtot[r] = m;
        fac[r] = exp2f(m_run[r] - m);
    }
    #pragma unroll
    for (int t = 0; t < 4; ++t)
        #pragma unroll
        for (int r = 0; r < 4; ++r)
            accw[wid][lg * 4 + r][t * 16 + l15] = acc[t][r] * fac[r];

    if (wid == 0 && l15 == 0) {
        #pragma unroll
        for (int r = 0; r < 4; ++r) {
            int row = lg * 4 + r;
            float L = 0.f;
            #pragma unroll
            for (int w = 0; w < 8; ++w)
                L += Lw[w][row] * exp2f(Mw[w][row] - mtot[r]);
            Ltot[row] = L;
        }
    }
    __syncthreads();

    #pragma unroll
    for (int j = 0; j < 2; ++j) {
        int o = tid + j * 512;
        int row = o >> 6, col = o & 63;
        float ssum = 0.f;
        #pragma unroll
        for (int w = 0; w < 8; ++w) ssum += accw[w][row][col];
        out[(b_ * 2048 + q0 + row) * 64 + col] = ssum / Ltot[row];
    }
}

extern "C" void kernel_launch(void* const* d_in, const int* in_sizes, int n_in,
                              void* d_out, int out_size, void* d_ws, size_t ws_size,
                              hipStream_t stream) {
    const float* x  = (const float*)d_in[0];
    const float* Wq = (const float*)d_in[1];
    const float* Wk = (const float*)d_in[2];
    const float* Wv = (const float*)d_in[3];
    float* out = (float*)d_out;

    char* ws = (char*)d_ws;
    short* Wt = (short*)ws;                              // 192*1024*2   = 393216 B
    short* Q  = (short*)(ws + 393216);                   // 8192*64*2    = 1048576 B
    short* K  = (short*)(ws + 393216 + 1048576);         // 1048576 B
    short* Vt = (short*)(ws + 393216 + 2 * 1048576);     // 1048576 B   (total ~3.4 MB)

    hipLaunchKernelGGL(wtrans,   dim3(768), dim3(256), 0, stream, Wq, Wk, Wv, Wt);
    hipLaunchKernelGGL(qkv_proj, dim3(512), dim3(256), 0, stream, x, Wt, Q, K, Vt);
    hipLaunchKernelGGL(attn,     dim3(512), dim3(512), 0, stream, Q, K, Vt, out);
}

// Round 7
// 70.854 us; speedup vs baseline: 1.4297x; 1.0078x over previous
//
#include <hip/hip_runtime.h>
#include <hip/hip_bf16.h>

// Self-attention, fused QKV: x[4,2048,1024] f32, Wq/Wk/Wv[1024,64] f32 -> out[4,2048,64] f32
// bf16 MFMA (16x16x32), fp32 accumulation.
//   K1: W -> Wt bf16 [192][1024] (k-major)
//   K2: QKV projection, 512 blocks x 4 waves, k-split x4, x read ONCE.
//       Q written pre-scaled by 0.125*log2(e) so attn softmax is pure exp2.
//   K3: flash attention, SWAPPED QK^T (mfma(K,Q) => lane owns ONE query, keys in regs):
//       softmax is 15 in-reg fmax + 2 shfl instead of 32 shfl. PV swapped too
//       (O^T = V^T P^T). split-KV x8, no barriers in KV loop, deterministic combine.

typedef __attribute__((ext_vector_type(8))) short bf16x8;
typedef __attribute__((ext_vector_type(4))) float f32x4;
typedef __attribute__((ext_vector_type(4))) unsigned short u16x4;

#define QSCALE 0.1803368801111832f   // 0.125 * log2(e); makes logits exp2-domain

__device__ __forceinline__ short f2bf(float f) {
    union { float f; unsigned u; } v; v.f = f;
    unsigned r = v.u + 0x7FFF + ((v.u >> 16) & 1);   // round-to-nearest-even
    return (short)(r >> 16);
}

// ---------------- K1: weight transpose + bf16 convert ----------------
__global__ __launch_bounds__(256) void wtrans(const float* __restrict__ Wq,
                                              const float* __restrict__ Wk,
                                              const float* __restrict__ Wv,
                                              short* __restrict__ Wt) {
    int idx = blockIdx.x * 256 + threadIdx.x;      // 0 .. 192*1024-1
    int n = idx >> 10;
    int d = idx & 1023;
    const float* W = (n < 64) ? Wq : (n < 128) ? Wk : Wv;
    Wt[idx] = f2bf(W[d * 64 + (n & 63)]);
}

// ---------------- K2: QKV projection ----------------
// grid 512 blocks x 256 thr (4 waves). Block: 16 rows x 192 cols, K=1024.
// wave wid = k-split index: K slice [wid*256, wid*256+256). x read exactly once.
__global__ __launch_bounds__(256) void qkv_proj(const float* __restrict__ x,
                                                const short* __restrict__ Wt,
                                                short* __restrict__ Q,
                                                short* __restrict__ K,
                                                short* __restrict__ Vt) {
    __shared__ float accs[3][16][196];
    int wid  = threadIdx.x >> 6;
    int lane = threadIdx.x & 63;
    int l15 = lane & 15, lg = lane >> 4;
    int mbase = blockIdx.x * 16;
    int row = mbase + l15;

    f32x4 acc[12];
    #pragma unroll
    for (int t = 0; t < 12; ++t) acc[t] = (f32x4){0.f, 0.f, 0.f, 0.f};

    int d0base = wid * 256;
    for (int d0 = d0base; d0 < d0base + 256; d0 += 32) {
        const float* xp = x + row * 1024 + d0 + lg * 8;
        float4 x0 = *(const float4*)xp;
        float4 x1 = *(const float4*)(xp + 4);
        bf16x8 a;
        a[0] = f2bf(x0.x); a[1] = f2bf(x0.y); a[2] = f2bf(x0.z); a[3] = f2bf(x0.w);
        a[4] = f2bf(x1.x); a[5] = f2bf(x1.y); a[6] = f2bf(x1.z); a[7] = f2bf(x1.w);
        #pragma unroll
        for (int t = 0; t < 12; ++t) {
            bf16x8 b = *(const bf16x8*)(Wt + (t * 16 + l15) * 1024 + d0 + lg * 8);
            acc[t] = __builtin_amdgcn_mfma_f32_16x16x32_bf16(a, b, acc[t], 0, 0, 0);
        }
    }

    if (wid != 0) {
        #pragma unroll
        for (int t = 0; t < 12; ++t)
            #pragma unroll
            for (int r = 0; r < 4; ++r)
                accs[wid - 1][lg * 4 + r][t * 16 + l15] = acc[t][r];
    }
    __syncthreads();
    if (wid == 0) {
        #pragma unroll
        for (int t = 0; t < 12; ++t) {
            int n = t * 16 + l15;
            #pragma unroll
            for (int r = 0; r < 4; ++r) {
                int qrow = lg * 4 + r;
                int m = mbase + qrow;
                float v = acc[t][r] + accs[0][qrow][n] + accs[1][qrow][n] + accs[2][qrow][n];
                if (n < 64) {
                    Q[m * 64 + n] = f2bf(v * QSCALE);
                } else if (n < 128) {
                    K[m * 64 + (n - 64)] = f2bf(v);
                } else {
                    int b_ = m >> 11, s_ = m & 2047;
                    Vt[(b_ * 64 + (n - 128)) * 2048 + s_] = f2bf(v);
                }
            }
        }
    }
}

// ---------------- K3: flash attention, swapped operands, split-KV ----------------
// grid = 4*128 = 512 blocks, 512 thr (8 waves). Each wave: same 16 queries, 256-key slice.
// s[kt][r] = S^T[key = kv+kt*16+lg*4+r][q = l15]  (lane owns ONE query)
// acc[t][r] = O^T[dk = t*16+lg*4+r][q = l15]
__global__ __launch_bounds__(512) void attn(const short* __restrict__ Q,
                                            const short* __restrict__ K,
                                            const short* __restrict__ Vt,
                                            float* __restrict__ out) {
    __shared__ float accw[8][16][68];    // scaled partial outputs (stride 68 -> 16B-aligned rows)
    __shared__ short P_lds[8][16][72];   // per-wave P [q][key], private per wave
    __shared__ float Mw[8][16];
    __shared__ float Lw[8][16];
    __shared__ float Ltot[16];

    int tid = threadIdx.x, wid = tid >> 6, lane = tid & 63;
    int l15 = lane & 15, lg = lane >> 4;
    int b_ = blockIdx.x >> 7;
    int q0 = (blockIdx.x & 127) * 16;
    const short* Kb = K + b_ * 2048 * 64;
    const short* Vb = Vt + b_ * 64 * 2048;

    // Q as B-operand: B[d][q], lane: q=l15, d=lg*8+j  -> plain row-major Q loads
    const short* Qp = Q + (b_ * 2048 + q0 + l15) * 64 + lg * 8;
    bf16x8 bq0 = *(const bf16x8*)Qp;
    bf16x8 bq1 = *(const bf16x8*)(Qp + 32);

    f32x4 acc[4];
    #pragma unroll
    for (int t = 0; t < 4; ++t) acc[t] = (f32x4){0.f, 0.f, 0.f, 0.f};
    float m_run = -INFINITY, l_run = 0.f;

    int kv0 = wid * 256;
    for (int kv = kv0; kv < kv0 + 256; kv += 64) {
        // S^T = K Q (exp2-domain logits)
        f32x4 s[4];
        #pragma unroll
        for (int kt = 0; kt < 4; ++kt) {
            const short* Kp = Kb + (kv + kt * 16 + l15) * 64 + lg * 8;
            bf16x8 ak0 = *(const bf16x8*)Kp;
            bf16x8 ak1 = *(const bf16x8*)(Kp + 32);
            f32x4 z = (f32x4){0.f, 0.f, 0.f, 0.f};
            z = __builtin_amdgcn_mfma_f32_16x16x32_bf16(ak0, bq0, z, 0, 0, 0);
            s[kt] = __builtin_amdgcn_mfma_f32_16x16x32_bf16(ak1, bq1, z, 0, 0, 0);
        }

        // per-lane online softmax: 16 keys in-register + 2 shfl across the 4-lane group
        float m01 = fmaxf(fmaxf(s[0][0], s[0][1]), fmaxf(s[0][2], s[0][3]));
        float m23 = fmaxf(fmaxf(s[1][0], s[1][1]), fmaxf(s[1][2], s[1][3]));
        float m45 = fmaxf(fmaxf(s[2][0], s[2][1]), fmaxf(s[2][2], s[2][3]));
        float m67 = fmaxf(fmaxf(s[3][0], s[3][1]), fmaxf(s[3][2], s[3][3]));
        float mt = fmaxf(fmaxf(m01, m23), fmaxf(m45, m67));
        mt = fmaxf(mt, __shfl_xor(mt, 16));
        mt = fmaxf(mt, __shfl_xor(mt, 32));
        float mn = fmaxf(m_run, mt);
        float c = exp2f(m_run - mn);
        m_run = mn;
        float rs = 0.f;
        #pragma unroll
        for (int kt = 0; kt < 4; ++kt)
            #pragma unroll
            for (int r = 0; r < 4; ++r) {
                float p = exp2f(s[kt][r] - mn);
                s[kt][r] = p;
                rs += p;
            }
        rs += __shfl_xor(rs, 16);
        rs += __shfl_xor(rs, 32);
        l_run = l_run * c + rs;
        #pragma unroll
        for (int t = 0; t < 4; ++t)
            #pragma unroll
            for (int r = 0; r < 4; ++r) acc[t][r] *= c;

        // P -> per-wave private LDS, layout [q][key] (read back as contiguous B-frags)
        #pragma unroll
        for (int kt = 0; kt < 4; ++kt) {
            u16x4 h;
            h[0] = (unsigned short)f2bf(s[kt][0]);
            h[1] = (unsigned short)f2bf(s[kt][1]);
            h[2] = (unsigned short)f2bf(s[kt][2]);
            h[3] = (unsigned short)f2bf(s[kt][3]);
            *(u16x4*)&P_lds[wid][l15][kt * 16 + lg * 4] = h;
        }

        // PV: O^T += V^T P^T.  A = V^T (plain Vt loads), B = P^T (contiguous LDS reads)
        #pragma unroll
        for (int ps = 0; ps < 2; ++ps) {
            bf16x8 bp = *(const bf16x8*)&P_lds[wid][l15][ps * 32 + lg * 8];
            #pragma unroll
            for (int t = 0; t < 4; ++t) {
                const short* Vp = Vb + (t * 16 + l15) * 2048 + kv + ps * 32 + lg * 8;
                bf16x8 av = *(const bf16x8*)Vp;
                acc[t] = __builtin_amdgcn_mfma_f32_16x16x32_bf16(av, bp, acc[t], 0, 0, 0);
            }
        }
    }

    // ---- deterministic split-KV combine ----
    if (lg == 0) {
        Mw[wid][l15] = m_run;
        Lw[wid][l15] = l_run;
    }
    __syncthreads();

    float mtot = Mw[0][l15];
    #pragma unroll
    for (int w = 1; w < 8; ++w) mtot = fmaxf(mtot, Mw[w][l15]);
    float fac = exp2f(m_run - mtot);
    #pragma unroll
    for (int t = 0; t < 4; ++t) {
        f32x4 v = acc[t];
        v[0] *= fac; v[1] *= fac; v[2] *= fac; v[3] *= fac;
        *(f32x4*)&accw[wid][l15][t * 16 + lg * 4] = v;
    }

    if (wid == 0 && lg == 0) {
        float L = 0.f;
        #pragma unroll
        for (int w = 0; w < 8; ++w)
            L += Lw[w][l15] * exp2f(Mw[w][l15] - mtot);
        Ltot[l15] = L;
    }
    __syncthreads();

    #pragma unroll
    for (int j = 0; j < 2; ++j) {
        int o = tid + j * 512;
        int row = o >> 6, col = o & 63;
        float ssum = 0.f;
        #pragma unroll
        for (int w = 0; w < 8; ++w) ssum += accw[w][row][col];
        out[(b_ * 2048 + q0 + row) * 64 + col] = ssum / Ltot[row];
    }
}

extern "C" void kernel_launch(void* const* d_in, const int* in_sizes, int n_in,
                              void* d_out, int out_size, void* d_ws, size_t ws_size,
                              hipStream_t stream) {
    const float* x  = (const float*)d_in[0];
    const float* Wq = (const float*)d_in[1];
    const float* Wk = (const float*)d_in[2];
    const float* Wv = (const float*)d_in[3];
    float* out = (float*)d_out;

    char* ws = (char*)d_ws;
    short* Wt = (short*)ws;                              // 192*1024*2   = 393216 B
    short* Q  = (short*)(ws + 393216);                   // 8192*64*2    = 1048576 B
    short* K  = (short*)(ws + 393216 + 1048576);         // 1048576 B
    short* Vt = (short*)(ws + 393216 + 2 * 1048576);     // 1048576 B   (total ~3.4 MB)

    hipLaunchKernelGGL(wtrans,   dim3(768), dim3(256), 0, stream, Wq, Wk, Wv, Wt);
    hipLaunchKernelGGL(qkv_proj, dim3(512), dim3(256), 0, stream, x, Wt, Q, K, Vt);
    hipLaunchKernelGGL(attn,     dim3(512), dim3(512), 0, stream, Q, K, Vt, out);
}